// Round 14
// baseline (295.562 us; speedup 1.0000x reference)
//
#include <hip/hip_runtime.h>
#include <hip/hip_fp16.h>

// GCN forward: 4 x (X@W -> gather-normalize-scatter -> +b, ReLU) -> mean pool -> linear
// N=50000 nodes, E=800000 edges, D=64, L=4, G=64.
// R14: packed __half2 gathers. fp16 row = 128B = 32 lanes x 4B, so the two half-waves
// gather TWO edges at once (evens/odds); each lane loads __half2 (features 2f2,2f2+1).
// Rounds of 32 edges, 16 batched loads in flight (R8's proven MLP, 2x edges/round;
// deg<=32 for ~99.97% nodes -> 1 round). Cross-half reduce = 2 shfl_xor (~1e-7 reorder,
// safe: bf16-rounded comparison gave absmax 0.0 even with fp16 stores in R13).
// Halves agg's load-instruction count; fill traffic (~45MB/layer) unchanged.
// NOTE: rocprof top-5 "fillBufferAligned 268MB" = harness d_ws poison, untimed; ignore.

#define D 64
#define BSHIFT 10                 // nodes per bucket = 1024
#define BNODES 1024
#define EPT 16                    // edges per thread in partition kernel
#define CB (256 * EPT)            // edges per block = 4096
#define CAP 24576                 // bucket region capacity (mean 16.3K)
#define SW(r, c4) ((c4) ^ (((r) >> 2) & 15))

// ---- setup: transpose all W (blocks 0..L-1) + zero bcnt (block L) --------

__global__ __launch_bounds__(256) void setup_kernel(
        const float* __restrict__ W, float* __restrict__ Wt,
        int* __restrict__ bcnt, int L) {
    int b = blockIdx.x;
    if (b < L) {
        const float* w = W + (size_t)b * D * D;
        float* wt = Wt + (size_t)b * D * D;
        for (int idx = threadIdx.x; idx < D * D; idx += 256) {
            int k = idx >> 6, c = idx & 63;
            wt[c * D + k] = w[idx];
        }
    } else {
        bcnt[threadIdx.x] = 0;
    }
}

// ---- CSR build: single-pass bucket partition into fixed-capacity regions -

__global__ __launch_bounds__(256) void partition_kernel(
        const int* __restrict__ src, const int* __restrict__ dst,
        int* __restrict__ bcnt, unsigned* __restrict__ eb, int e) {
    __shared__ int cB[256], gb[256], cur[256];
    int t = threadIdx.x;
    cB[t] = 0;
    __syncthreads();
    int base = blockIdx.x * CB;
    int ps[EPT], pd[EPT];
    #pragma unroll
    for (int k = 0; k < EPT; ++k) {
        int i = base + t + k * 256;
        if (i < e) {
            ps[k] = src[i];
            pd[k] = dst[i];
            atomicAdd(&cB[pd[k] >> BSHIFT], 1);
        } else {
            pd[k] = -1;
        }
    }
    __syncthreads();
    if (cB[t]) gb[t] = atomicAdd(&bcnt[t], cB[t]);   // reserve chunk in bucket t
    cur[t] = 0;
    __syncthreads();
    #pragma unroll
    for (int k = 0; k < EPT; ++k) {
        if (pd[k] >= 0) {
            int b = pd[k] >> BSHIFT;
            int p = atomicAdd(&cur[b], 1);
            eb[(size_t)b * CAP + gb[b] + p] =
                (unsigned)(ps[k] & 0xFFFF) | ((unsigned)(pd[k] & (BNODES - 1)) << 16);
        }
    }
}

// one block per bucket: bucket offset (prefix via LDS atomics), node hist,
// local scan -> absolute row_start, dinv, LDS-cursor scatter.
__global__ __launch_bounds__(BNODES) void build_csr(
        const unsigned* __restrict__ eb, const int* __restrict__ bcnt,
        int* __restrict__ row_start, float* __restrict__ dinv,
        int* __restrict__ csr_src, int n, int e) {
    __shared__ int sh[BNODES];
    __shared__ int cur[BNODES];
    __shared__ int boffsh;
    int b = blockIdx.x, t = threadIdx.x;
    if (t == 0) boffsh = 0;
    __syncthreads();
    if (t < b) atomicAdd(&boffsh, bcnt[t]);       // exclusive prefix of bucket counts
    int cnt = bcnt[b];
    const unsigned* ebb = eb + (size_t)b * CAP;
    sh[t] = 0;
    __syncthreads();
    int boff = boffsh;
    for (int i = t; i < cnt; i += BNODES) atomicAdd(&sh[ebb[i] >> 16], 1);
    __syncthreads();
    int c = sh[t];
    __syncthreads();
    for (int off = 1; off < BNODES; off <<= 1) {
        int vp = (t >= off) ? sh[t - off] : 0;
        __syncthreads();
        sh[t] += vp;
        __syncthreads();
    }
    int a = sh[t] - c + boff;             // absolute row offset
    int node = b * BNODES + t;
    if (node < n) {
        row_start[node] = a;
        dinv[node] = 1.0f / sqrtf((float)(c + 1));
    }
    if (b == 0 && t == 0) row_start[n] = e;
    cur[t] = a;
    __syncthreads();
    for (int i = t; i < cnt; i += BNODES) {
        unsigned v = ebb[i];
        int p = atomicAdd(&cur[v >> 16], 1);
        csr_src[p] = (int)(v & 0xFFFFu);
    }
}

// ---- layer 0: H0 = fp16( dinv .* (X @ W0) ), 4x4 register tile -----------

__global__ __launch_bounds__(256, 3) void matmul_kernel(
        const float* __restrict__ X, const float* __restrict__ Wt,
        const float* __restrict__ dinv, __half* __restrict__ H, int n) {
    __shared__ float4 Xs[64 * 16];   // 16 KB, swizzled
    __shared__ float4 Ws[64 * 16];   // 16 KB, swizzled (Wt rows = W cols)
    int t = threadIdx.x;
    int rowBase = blockIdx.x * 64;
    const float4* X4 = (const float4*)X;
    const float4* Wt4 = (const float4*)Wt;
    #pragma unroll
    for (int p = 0; p < 4; ++p) {
        int rl = (t >> 4) + 16 * p;
        int c4 = t & 15;
        int r = rowBase + rl;
        float4 v = make_float4(0.f, 0.f, 0.f, 0.f);
        if (r < n) v = X4[(size_t)r * 16 + c4];
        Xs[rl * 16 + SW(rl, c4)] = v;
        Ws[rl * 16 + SW(rl, c4)] = Wt4[rl * 16 + c4];
    }
    __syncthreads();
    int wv = t >> 6, lane = t & 63;
    int rg = lane >> 2, cg = lane & 3;
    int r0 = rg * 4;
    int c0 = wv * 16 + cg * 4;
    float acc[4][4] = {};
    #pragma unroll 2
    for (int k4 = 0; k4 < 16; ++k4) {
        float4 xv[4], wvv[4];
        #pragma unroll
        for (int i = 0; i < 4; ++i) xv[i] = Xs[(r0 + i) * 16 + SW(r0 + i, k4)];
        #pragma unroll
        for (int j = 0; j < 4; ++j) wvv[j] = Ws[(c0 + j) * 16 + SW(c0 + j, k4)];
        #pragma unroll
        for (int i = 0; i < 4; ++i)
            #pragma unroll
            for (int j = 0; j < 4; ++j) {
                acc[i][j] += xv[i].x * wvv[j].x;
                acc[i][j] += xv[i].y * wvv[j].y;
                acc[i][j] += xv[i].z * wvv[j].z;
                acc[i][j] += xv[i].w * wvv[j].w;
            }
    }
    #pragma unroll
    for (int i = 0; i < 4; ++i) {
        int r = rowBase + r0 + i;
        if (r < n) {
            float dr = dinv[r];
            ushort4 o;
            o.x = __half_as_ushort(__float2half(dr * acc[i][0]));
            o.y = __half_as_ushort(__float2half(dr * acc[i][1]));
            o.z = __half_as_ushort(__float2half(dr * acc[i][2]));
            o.w = __half_as_ushort(__float2half(dr * acc[i][3]));
            *(ushort4*)&H[(size_t)r * D + c0] = o;   // 8B store
        }
    }
}

// ---- packed-gather core: sum of H2 rows over edges [s, s+deg) ------------
// Wave = 1 node. half = lane>>5 takes even/odd edges; f2 = lane&31 the __half2
// feature pair. Rounds of 32 edges, 16 batched loads in flight per lane.
// Returns per-lane partial; caller reduces across halves (2x shfl_xor).

__device__ __forceinline__ float2 gather_sum(
        const __half2* __restrict__ H2, const int* __restrict__ csr_src,
        int s, int deg, int half, int f2) {
    float2 acc = make_float2(0.f, 0.f);
    int li = (half << 5) - 32 + f2;  // unused; silence
    (void)li;
    for (int base = 0; base < deg; base += 32) {
        int rem = deg - base;                        // wave-uniform
        int idx = 0;
        int lj = f2;                                 // lanes load 32 indices (2x dup)
        if (lj < rem) idx = csr_src[s + base + lj];
        float2 h[16];
        #pragma unroll
        for (int ii = 0; ii < 16; ++ii) {
            int el = 2 * ii + half;
            int u = __shfl(idx, el & 31, 64);
            if (el < rem) {
                h[ii] = __half22float2(H2[(size_t)u * 32 + f2]);
            } else {
                h[ii] = make_float2(0.f, 0.f);
            }
        }
        #pragma unroll
        for (int ii = 0; ii < 16; ++ii) {
            acc.x += h[ii].x;
            acc.y += h[ii].y;
        }
    }
    return acc;
}

// ---- layers 0..2: aggregate(fp16 in, fp32 accum) + bias + ReLU + next W --

__global__ __launch_bounds__(256) void agg_fused(
        const __half* __restrict__ H, const int* __restrict__ csr_src,
        const int* __restrict__ row_start, const float* __restrict__ dinv,
        const float* __restrict__ bias, const float* __restrict__ Wtn,
        __half* __restrict__ out, int n) {
    __shared__ float4 Wsh4[D * 16];               // Wt(l+1) swizzled, 16 KB
    __shared__ __align__(16) float2 rowsh[4][32]; // 4 waves x 64 feats
    int t = threadIdx.x;
    {
        const float4* Wt4 = (const float4*)Wtn;
        #pragma unroll
        for (int p = 0; p < 4; ++p) {
            int i = t + p * 256;
            int c = i >> 4, k4 = i & 15;
            Wsh4[(c << 4) | (k4 ^ (c & 15))] = Wt4[i];
        }
    }
    __syncthreads();                     // all threads reach (no early return)
    int wave = t >> 6, lane = t & 63;
    int half = lane >> 5, f2 = lane & 31;
    int v = blockIdx.x * 4 + wave;
    bool active = v < n;
    const __half2* H2 = (const __half2*)H;
    float dv = 0.f;
    float2 acc = make_float2(0.f, 0.f);
    if (active) {
        dv = dinv[v];
        int s = row_start[v];
        int deg = row_start[v + 1] - s;
        acc = gather_sum(H2, csr_src, s, deg, half, f2);
    }
    acc.x += __shfl_xor(acc.x, 32, 64);
    acc.y += __shfl_xor(acc.y, 32, 64);
    if (active && half == 0) {
        float2 self = __half22float2(H2[(size_t)v * 32 + f2]);
        float2 b2 = ((const float2*)bias)[f2];
        float2 o;
        o.x = fmaxf(dv * (self.x + acc.x) + b2.x, 0.f);
        o.y = fmaxf(dv * (self.y + acc.y) + b2.y, 0.f);
        rowsh[wave][f2] = o;             // wave-local; LDS ops in-order per wave
    }
    if (active) {
        const float4* r4p = (const float4*)&rowsh[wave][0];
        float accT = 0.f;
        #pragma unroll
        for (int k4 = 0; k4 < 16; ++k4) {
            float4 r = r4p[k4];                              // uniform broadcast
            float4 w = Wsh4[(lane << 4) | (k4 ^ (lane & 15))];
            accT += r.x * w.x;           // k = 4*k4+0,1,2,3 ascending
            accT += r.y * w.y;
            accT += r.z * w.z;
            accT += r.w * w.w;
        }
        out[(size_t)v * D + lane] = __float2half(dv * accT);
    }
}

// ---- layer 3: aggregate(fp16 in) + bias + ReLU -> fp32 out ---------------

__global__ __launch_bounds__(256) void agg_kernel(
        const __half* __restrict__ H, const int* __restrict__ csr_src,
        const int* __restrict__ row_start, const float* __restrict__ dinv,
        const float* __restrict__ bias, float* __restrict__ out, int n) {
    int t = threadIdx.x;
    int wave = t >> 6, lane = t & 63;
    int half = lane >> 5, f2 = lane & 31;
    int v = blockIdx.x * 4 + wave;
    if (v >= n) return;
    const __half2* H2 = (const __half2*)H;
    float dv = dinv[v];
    int s = row_start[v];
    int deg = row_start[v + 1] - s;
    float2 acc = gather_sum(H2, csr_src, s, deg, half, f2);
    acc.x += __shfl_xor(acc.x, 32, 64);
    acc.y += __shfl_xor(acc.y, 32, 64);
    if (half == 0) {
        float2 self = __half22float2(H2[(size_t)v * 32 + f2]);
        float2 b2 = ((const float2*)bias)[f2];
        float2 o;
        o.x = fmaxf(dv * (self.x + acc.x) + b2.x, 0.f);
        o.y = fmaxf(dv * (self.y + acc.y) + b2.y, 0.f);
        ((float2*)out)[(size_t)v * 32 + f2] = o;
    }
}

// ---- mean pool + final linear, one block (1024 thr) per graph ------------

__device__ __forceinline__ int lower_bound_g(const int* __restrict__ b, int n, int g) {
    int lo = 0, hi = n;
    while (lo < hi) { int m = (lo + hi) >> 1; if (b[m] < g) lo = m + 1; else hi = m; }
    return lo;
}

__global__ __launch_bounds__(1024) void pool_final(
        const float* __restrict__ X, const int* __restrict__ batch,
        const float* __restrict__ linW, const float* __restrict__ linb,
        float* __restrict__ out, int n) {
    __shared__ float sh[16][64];
    int g = blockIdx.x;
    int gs = lower_bound_g(batch, n, g);
    int ge = lower_bound_g(batch, n, g + 1);
    int wv = threadIdx.x >> 6, lane = threadIdx.x & 63;
    float acc = 0.f;
    for (int r = gs + wv; r < ge; r += 16)
        acc += X[(size_t)r * D + lane];
    sh[wv][lane] = acc;
    __syncthreads();
    if (wv == 0) {
        float tot = 0.f;
        #pragma unroll
        for (int i = 0; i < 16; ++i) tot += sh[i][lane];
        float cnt = fmaxf((float)(ge - gs), 1.f);
        float p = (tot / cnt) * linW[lane];
        #pragma unroll
        for (int off = 32; off > 0; off >>= 1) p += __shfl_down(p, off, 64);
        if (lane == 0) out[g] = p + linb[0];
    }
}

// ---- orchestration -------------------------------------------------------

extern "C" void kernel_launch(void* const* d_in, const int* in_sizes, int n_in,
                              void* d_out, int out_size, void* d_ws, size_t ws_size,
                              hipStream_t stream) {
    const float* x      = (const float*)d_in[0];  // [N,64]
    const float* conv_W = (const float*)d_in[1];  // [4,64,64]
    const float* conv_b = (const float*)d_in[2];  // [4,64]
    const float* lin_W  = (const float*)d_in[3];  // [64,1]
    const float* lin_b  = (const float*)d_in[4];  // [1]
    const int*   edge   = (const int*)d_in[5];    // [2,E]
    const int*   batch  = (const int*)d_in[6];    // [N]

    const int n = in_sizes[0] / D;
    const int e = in_sizes[5] / 2;
    const int L = in_sizes[1] / (D * D);          // 4
    const int G = out_size;

    const int* esrc = edge;
    const int* edst = edge + e;

    // workspace layout (256B aligned)
    char* ws = (char*)d_ws;
    size_t off = 0;
    auto alloc = [&](size_t bytes) -> void* {
        void* p = ws + off;
        off += (bytes + 255) & ~(size_t)255;
        return p;
    };
    const int nb = (n + BNODES - 1) / BNODES;     // buckets (49)
    int*    bcnt      = (int*)alloc(256 * 4);
    float*  dinv      = (float*)alloc((size_t)n * 4);
    int*    row_start = (int*)alloc((size_t)(n + 1) * 4);
    int*    csr_src   = (int*)alloc((size_t)e * 4);
    float*  wtbuf     = (float*)alloc((size_t)L * D * D * 4);
    __half* h16a      = (__half*)alloc((size_t)n * D * 2);
    __half* h16b      = (__half*)alloc((size_t)n * D * 2);
    float*  hf32      = (float*)alloc((size_t)n * D * 4);
    unsigned* eb      = (unsigned*)hf32;          // nb*CAP*4 = 4.8MB < 12.8MB hf32;
                                                  // eb dead before layer-3 writes hf32
    (void)ws_size;

    setup_kernel<<<L + 1, 256, 0, stream>>>(conv_W, wtbuf, bcnt, L);

    const int pb = (e + CB - 1) / CB;             // partition blocks (196)
    partition_kernel<<<pb, 256, 0, stream>>>(esrc, edst, bcnt, eb, e);
    build_csr       <<<nb, BNODES, 0, stream>>>(eb, bcnt, row_start, dinv,
                                                csr_src, n, e);

    const int ablocks = (n + 3) / 4;

    // layer 0 linear transform (external input) -> fp16 H0
    matmul_kernel<<<(n + 63) / 64, 256, 0, stream>>>(x, wtbuf, dinv, h16a, n);
    // layers 0..2: agg + fused next-layer transform (ping-pong h16a/h16b)
    agg_fused<<<ablocks, 256, 0, stream>>>(h16a, csr_src, row_start, dinv,
                                           conv_b + 0 * D, wtbuf + 1 * D * D, h16b, n);
    agg_fused<<<ablocks, 256, 0, stream>>>(h16b, csr_src, row_start, dinv,
                                           conv_b + 1 * D, wtbuf + 2 * D * D, h16a, n);
    agg_fused<<<ablocks, 256, 0, stream>>>(h16a, csr_src, row_start, dinv,
                                           conv_b + 2 * D, wtbuf + 3 * D * D, h16b, n);
    // layer 3: plain agg -> fp32
    agg_kernel<<<ablocks, 256, 0, stream>>>(h16b, csr_src, row_start, dinv,
                                            conv_b + 3 * D, hf32, n);

    // pool + final linear (single kernel)
    pool_final<<<G, 1024, 0, stream>>>(hf32, batch, lin_W, lin_b, (float*)d_out, n);
}

// Round 15
// 235.127 us; speedup vs baseline: 1.2570x; 1.2570x over previous
//
#include <hip/hip_runtime.h>
#include <hip/hip_fp16.h>

// GCN forward: 4 x (X@W -> gather-normalize-scatter -> +b, ReLU) -> mean pool -> linear
// N=50000 nodes, E=800000 edges, D=64, L=4, G=64.
// R15: 2 nodes per wave (half-wave = one node), __half2 feature pairs. Each half-wave:
// 32 lanes x half2 = one full 128B row per gather instruction -- halves the gather
// instruction count vs R13 (64 lanes x 2B on the same row) with NO shfl (R14's mistake)
// and NO padding loops. Batch-8 ascending adds == R13's sequential order -> bitwise
// identical. Transform = two sequential per-node passes of R13's swizzled-b128 dot.
// NOTE: rocprof top-5 "fillBufferAligned 268MB" = harness d_ws poison, untimed; ignore.

#define D 64
#define BSHIFT 10                 // nodes per bucket = 1024
#define BNODES 1024
#define EPT 16                    // edges per thread in partition kernel
#define CB (256 * EPT)            // edges per block = 4096
#define CAP 24576                 // bucket region capacity (mean 16.3K)
#define SW(r, c4) ((c4) ^ (((r) >> 2) & 15))

// ---- setup: transpose all W (blocks 0..L-1) + zero bcnt (block L) --------

__global__ __launch_bounds__(256) void setup_kernel(
        const float* __restrict__ W, float* __restrict__ Wt,
        int* __restrict__ bcnt, int L) {
    int b = blockIdx.x;
    if (b < L) {
        const float* w = W + (size_t)b * D * D;
        float* wt = Wt + (size_t)b * D * D;
        for (int idx = threadIdx.x; idx < D * D; idx += 256) {
            int k = idx >> 6, c = idx & 63;
            wt[c * D + k] = w[idx];
        }
    } else {
        bcnt[threadIdx.x] = 0;
    }
}

// ---- CSR build: single-pass bucket partition into fixed-capacity regions -

__global__ __launch_bounds__(256) void partition_kernel(
        const int* __restrict__ src, const int* __restrict__ dst,
        int* __restrict__ bcnt, unsigned* __restrict__ eb, int e) {
    __shared__ int cB[256], gb[256], cur[256];
    int t = threadIdx.x;
    cB[t] = 0;
    __syncthreads();
    int base = blockIdx.x * CB;
    int ps[EPT], pd[EPT];
    #pragma unroll
    for (int k = 0; k < EPT; ++k) {
        int i = base + t + k * 256;
        if (i < e) {
            ps[k] = src[i];
            pd[k] = dst[i];
            atomicAdd(&cB[pd[k] >> BSHIFT], 1);
        } else {
            pd[k] = -1;
        }
    }
    __syncthreads();
    if (cB[t]) gb[t] = atomicAdd(&bcnt[t], cB[t]);   // reserve chunk in bucket t
    cur[t] = 0;
    __syncthreads();
    #pragma unroll
    for (int k = 0; k < EPT; ++k) {
        if (pd[k] >= 0) {
            int b = pd[k] >> BSHIFT;
            int p = atomicAdd(&cur[b], 1);
            eb[(size_t)b * CAP + gb[b] + p] =
                (unsigned)(ps[k] & 0xFFFF) | ((unsigned)(pd[k] & (BNODES - 1)) << 16);
        }
    }
}

// one block per bucket: bucket offset (prefix via LDS atomics), node hist,
// local scan -> absolute row_start, dinv, LDS-cursor scatter.
__global__ __launch_bounds__(BNODES) void build_csr(
        const unsigned* __restrict__ eb, const int* __restrict__ bcnt,
        int* __restrict__ row_start, float* __restrict__ dinv,
        int* __restrict__ csr_src, int n, int e) {
    __shared__ int sh[BNODES];
    __shared__ int cur[BNODES];
    __shared__ int boffsh;
    int b = blockIdx.x, t = threadIdx.x;
    if (t == 0) boffsh = 0;
    __syncthreads();
    if (t < b) atomicAdd(&boffsh, bcnt[t]);       // exclusive prefix of bucket counts
    int cnt = bcnt[b];
    const unsigned* ebb = eb + (size_t)b * CAP;
    sh[t] = 0;
    __syncthreads();
    int boff = boffsh;
    for (int i = t; i < cnt; i += BNODES) atomicAdd(&sh[ebb[i] >> 16], 1);
    __syncthreads();
    int c = sh[t];
    __syncthreads();
    for (int off = 1; off < BNODES; off <<= 1) {
        int vp = (t >= off) ? sh[t - off] : 0;
        __syncthreads();
        sh[t] += vp;
        __syncthreads();
    }
    int a = sh[t] - c + boff;             // absolute row offset
    int node = b * BNODES + t;
    if (node < n) {
        row_start[node] = a;
        dinv[node] = 1.0f / sqrtf((float)(c + 1));
    }
    if (b == 0 && t == 0) row_start[n] = e;
    cur[t] = a;
    __syncthreads();
    for (int i = t; i < cnt; i += BNODES) {
        unsigned v = ebb[i];
        int p = atomicAdd(&cur[v >> 16], 1);
        csr_src[p] = (int)(v & 0xFFFFu);
    }
}

// ---- layer 0: H0 = fp16( dinv .* (X @ W0) ), 4x4 register tile -----------

__global__ __launch_bounds__(256, 3) void matmul_kernel(
        const float* __restrict__ X, const float* __restrict__ Wt,
        const float* __restrict__ dinv, __half* __restrict__ H, int n) {
    __shared__ float4 Xs[64 * 16];   // 16 KB, swizzled
    __shared__ float4 Ws[64 * 16];   // 16 KB, swizzled (Wt rows = W cols)
    int t = threadIdx.x;
    int rowBase = blockIdx.x * 64;
    const float4* X4 = (const float4*)X;
    const float4* Wt4 = (const float4*)Wt;
    #pragma unroll
    for (int p = 0; p < 4; ++p) {
        int rl = (t >> 4) + 16 * p;
        int c4 = t & 15;
        int r = rowBase + rl;
        float4 v = make_float4(0.f, 0.f, 0.f, 0.f);
        if (r < n) v = X4[(size_t)r * 16 + c4];
        Xs[rl * 16 + SW(rl, c4)] = v;
        Ws[rl * 16 + SW(rl, c4)] = Wt4[rl * 16 + c4];
    }
    __syncthreads();
    int wv = t >> 6, lane = t & 63;
    int rg = lane >> 2, cg = lane & 3;
    int r0 = rg * 4;
    int c0 = wv * 16 + cg * 4;
    float acc[4][4] = {};
    #pragma unroll 2
    for (int k4 = 0; k4 < 16; ++k4) {
        float4 xv[4], wvv[4];
        #pragma unroll
        for (int i = 0; i < 4; ++i) xv[i] = Xs[(r0 + i) * 16 + SW(r0 + i, k4)];
        #pragma unroll
        for (int j = 0; j < 4; ++j) wvv[j] = Ws[(c0 + j) * 16 + SW(c0 + j, k4)];
        #pragma unroll
        for (int i = 0; i < 4; ++i)
            #pragma unroll
            for (int j = 0; j < 4; ++j) {
                acc[i][j] += xv[i].x * wvv[j].x;
                acc[i][j] += xv[i].y * wvv[j].y;
                acc[i][j] += xv[i].z * wvv[j].z;
                acc[i][j] += xv[i].w * wvv[j].w;
            }
    }
    #pragma unroll
    for (int i = 0; i < 4; ++i) {
        int r = rowBase + r0 + i;
        if (r < n) {
            float dr = dinv[r];
            ushort4 o;
            o.x = __half_as_ushort(__float2half(dr * acc[i][0]));
            o.y = __half_as_ushort(__float2half(dr * acc[i][1]));
            o.z = __half_as_ushort(__float2half(dr * acc[i][2]));
            o.w = __half_as_ushort(__float2half(dr * acc[i][3]));
            *(ushort4*)&H[(size_t)r * D + c0] = o;   // 8B store
        }
    }
}

// ---- packed-gather core (per half-wave): sum of half2 rows, batch-8 ------
// 32 lanes x __half2 = one full 128B row per gather. Adds strictly ascending
// (batch-8 sequential == R13's order). Guarded values, no shfl, no padding.

__device__ __forceinline__ float2 gather_sum8(
        const __half2* __restrict__ H2, const int* __restrict__ csr_src,
        int s, int deg, int f2) {
    float2 acc = make_float2(0.f, 0.f);
    #pragma unroll 1
    for (int base = 0; base < deg; base += 8) {
        int u[8];
        float2 h[8];
        #pragma unroll
        for (int k = 0; k < 8; ++k)
            u[k] = (base + k < deg) ? csr_src[s + base + k] : -1;
        #pragma unroll
        for (int k = 0; k < 8; ++k)
            h[k] = (u[k] >= 0) ? __half22float2(H2[(size_t)u[k] * 32 + f2])
                               : make_float2(0.f, 0.f);
        #pragma unroll
        for (int k = 0; k < 8; ++k) {
            acc.x += h[k].x;
            acc.y += h[k].y;
        }
    }
    return acc;
}

// ---- layers 0..2: aggregate(fp16, fp32 accum) + bias + ReLU + next W -----
// Wave = 2 nodes (one per half-wave). Transform = 2 sequential per-node passes
// of the R13 swizzled-b128 dot (k ascending 0..63) -> bitwise identical.

__global__ __launch_bounds__(256) void agg_fused(
        const __half* __restrict__ H, const int* __restrict__ csr_src,
        const int* __restrict__ row_start, const float* __restrict__ dinv,
        const float* __restrict__ bias, const float* __restrict__ Wtn,
        __half* __restrict__ out, int n) {
    __shared__ float4 Wsh4[D * 16];               // Wt(l+1) swizzled, 16 KB
    __shared__ __align__(16) float2 rowsh[8][32]; // 8 nodes per block
    int t = threadIdx.x;
    {
        const float4* Wt4 = (const float4*)Wtn;
        #pragma unroll
        for (int p = 0; p < 4; ++p) {
            int i = t + p * 256;
            int c = i >> 4, k4 = i & 15;
            Wsh4[(c << 4) | (k4 ^ (c & 15))] = Wt4[i];
        }
    }
    __syncthreads();                     // all threads reach (no early return)
    int wave = t >> 6, lane = t & 63;
    int half = lane >> 5, f2 = lane & 31;
    int vpair = blockIdx.x * 8 + wave * 2;
    int v = vpair + half;                // this half-wave's node
    bool active = v < n;
    const __half2* H2 = (const __half2*)H;
    if (active) {
        float dv = dinv[v];
        int s = row_start[v];
        int deg = row_start[v + 1] - s;
        float2 acc = gather_sum8(H2, csr_src, s, deg, f2);
        float2 self = __half22float2(H2[(size_t)v * 32 + f2]);
        float2 b2 = ((const float2*)bias)[f2];
        float2 o;
        o.x = fmaxf(dv * (self.x + acc.x) + b2.x, 0.f);
        o.y = fmaxf(dv * (self.y + acc.y) + b2.y, 0.f);
        rowsh[wave * 2 + half][f2] = o;  // wave-local; LDS ops in-order per wave
    }
    #pragma unroll
    for (int p = 0; p < 2; ++p) {        // transform node vpair+p, all 64 lanes
        int vv = vpair + p;
        if (vv < n) {
            const float4* r4p = (const float4*)&rowsh[wave * 2 + p][0];
            float accT = 0.f;
            #pragma unroll
            for (int k4 = 0; k4 < 16; ++k4) {
                float4 r = r4p[k4];                          // uniform broadcast
                float4 w = Wsh4[(lane << 4) | (k4 ^ (lane & 15))];
                accT += r.x * w.x;       // k = 4*k4+0,1,2,3 ascending
                accT += r.y * w.y;
                accT += r.z * w.z;
                accT += r.w * w.w;
            }
            out[(size_t)vv * D + lane] = __float2half(dinv[vv] * accT);
        }
    }
}

// ---- layer 3: aggregate(fp16 in) + bias + ReLU -> fp32 out ---------------

__global__ __launch_bounds__(256) void agg_kernel(
        const __half* __restrict__ H, const int* __restrict__ csr_src,
        const int* __restrict__ row_start, const float* __restrict__ dinv,
        const float* __restrict__ bias, float* __restrict__ out, int n) {
    int t = threadIdx.x;
    int wave = t >> 6, lane = t & 63;
    int half = lane >> 5, f2 = lane & 31;
    int v = blockIdx.x * 8 + wave * 2 + half;
    if (v >= n) return;                  // per-half exit ok: no cross-lane ops below
    const __half2* H2 = (const __half2*)H;
    float dv = dinv[v];
    int s = row_start[v];
    int deg = row_start[v + 1] - s;
    float2 acc = gather_sum8(H2, csr_src, s, deg, f2);
    float2 self = __half22float2(H2[(size_t)v * 32 + f2]);
    float2 b2 = ((const float2*)bias)[f2];
    float2 o;
    o.x = fmaxf(dv * (self.x + acc.x) + b2.x, 0.f);
    o.y = fmaxf(dv * (self.y + acc.y) + b2.y, 0.f);
    ((float2*)out)[(size_t)v * 32 + f2] = o;
}

// ---- mean pool + final linear, one block (1024 thr) per graph ------------

__device__ __forceinline__ int lower_bound_g(const int* __restrict__ b, int n, int g) {
    int lo = 0, hi = n;
    while (lo < hi) { int m = (lo + hi) >> 1; if (b[m] < g) lo = m + 1; else hi = m; }
    return lo;
}

__global__ __launch_bounds__(1024) void pool_final(
        const float* __restrict__ X, const int* __restrict__ batch,
        const float* __restrict__ linW, const float* __restrict__ linb,
        float* __restrict__ out, int n) {
    __shared__ float sh[16][64];
    int g = blockIdx.x;
    int gs = lower_bound_g(batch, n, g);
    int ge = lower_bound_g(batch, n, g + 1);
    int wv = threadIdx.x >> 6, lane = threadIdx.x & 63;
    float acc = 0.f;
    for (int r = gs + wv; r < ge; r += 16)
        acc += X[(size_t)r * D + lane];
    sh[wv][lane] = acc;
    __syncthreads();
    if (wv == 0) {
        float tot = 0.f;
        #pragma unroll
        for (int i = 0; i < 16; ++i) tot += sh[i][lane];
        float cnt = fmaxf((float)(ge - gs), 1.f);
        float p = (tot / cnt) * linW[lane];
        #pragma unroll
        for (int off = 32; off > 0; off >>= 1) p += __shfl_down(p, off, 64);
        if (lane == 0) out[g] = p + linb[0];
    }
}

// ---- orchestration -------------------------------------------------------

extern "C" void kernel_launch(void* const* d_in, const int* in_sizes, int n_in,
                              void* d_out, int out_size, void* d_ws, size_t ws_size,
                              hipStream_t stream) {
    const float* x      = (const float*)d_in[0];  // [N,64]
    const float* conv_W = (const float*)d_in[1];  // [4,64,64]
    const float* conv_b = (const float*)d_in[2];  // [4,64]
    const float* lin_W  = (const float*)d_in[3];  // [64,1]
    const float* lin_b  = (const float*)d_in[4];  // [1]
    const int*   edge   = (const int*)d_in[5];    // [2,E]
    const int*   batch  = (const int*)d_in[6];    // [N]

    const int n = in_sizes[0] / D;
    const int e = in_sizes[5] / 2;
    const int L = in_sizes[1] / (D * D);          // 4
    const int G = out_size;

    const int* esrc = edge;
    const int* edst = edge + e;

    // workspace layout (256B aligned)
    char* ws = (char*)d_ws;
    size_t off = 0;
    auto alloc = [&](size_t bytes) -> void* {
        void* p = ws + off;
        off += (bytes + 255) & ~(size_t)255;
        return p;
    };
    const int nb = (n + BNODES - 1) / BNODES;     // buckets (49)
    int*    bcnt      = (int*)alloc(256 * 4);
    float*  dinv      = (float*)alloc((size_t)n * 4);
    int*    row_start = (int*)alloc((size_t)(n + 1) * 4);
    int*    csr_src   = (int*)alloc((size_t)e * 4);
    float*  wtbuf     = (float*)alloc((size_t)L * D * D * 4);
    __half* h16a      = (__half*)alloc((size_t)n * D * 2);
    __half* h16b      = (__half*)alloc((size_t)n * D * 2);
    float*  hf32      = (float*)alloc((size_t)n * D * 4);
    unsigned* eb      = (unsigned*)hf32;          // nb*CAP*4 = 4.8MB < 12.8MB hf32;
                                                  // eb dead before layer-3 writes hf32
    (void)ws_size;

    setup_kernel<<<L + 1, 256, 0, stream>>>(conv_W, wtbuf, bcnt, L);

    const int pb = (e + CB - 1) / CB;             // partition blocks (196)
    partition_kernel<<<pb, 256, 0, stream>>>(esrc, edst, bcnt, eb, e);
    build_csr       <<<nb, BNODES, 0, stream>>>(eb, bcnt, row_start, dinv,
                                                csr_src, n, e);

    const int ablocks = (n + 7) / 8;              // 8 nodes per block (2 per wave)

    // layer 0 linear transform (external input) -> fp16 H0
    matmul_kernel<<<(n + 63) / 64, 256, 0, stream>>>(x, wtbuf, dinv, h16a, n);
    // layers 0..2: agg + fused next-layer transform (ping-pong h16a/h16b)
    agg_fused<<<ablocks, 256, 0, stream>>>(h16a, csr_src, row_start, dinv,
                                           conv_b + 0 * D, wtbuf + 1 * D * D, h16b, n);
    agg_fused<<<ablocks, 256, 0, stream>>>(h16b, csr_src, row_start, dinv,
                                           conv_b + 1 * D, wtbuf + 2 * D * D, h16a, n);
    agg_fused<<<ablocks, 256, 0, stream>>>(h16a, csr_src, row_start, dinv,
                                           conv_b + 2 * D, wtbuf + 3 * D * D, h16b, n);
    // layer 3: plain agg -> fp32
    agg_kernel<<<ablocks, 256, 0, stream>>>(h16b, csr_src, row_start, dinv,
                                            conv_b + 3 * D, hf32, n);

    // pool + final linear (single kernel)
    pool_final<<<G, 1024, 0, stream>>>(hf32, batch, lin_W, lin_b, (float*)d_out, n);
}